// Round 8
// baseline (176.145 us; speedup 1.0000x reference)
//
#include <hip/hip_runtime.h>
#include <hip/hip_bf16.h>

// DotProductAttention B=2,H=16,S=2048,D=64 fp32 in/out, int32 mask (B,1,S,S).
// R10: intra-block KV-split + 2-q-group amortization.
//  R9 A/B: barrier drain was NOT the cost; LDS pipe ~79% busy is (51us of
//  64.7). R7 halved LDS traffic but halved TLP (latency-bound); R8 restored
//  TLP via key-split but paid 14us global combine. R10 does both inside one
//  block: 8 waves, wave w = q-group (w&3, 32 rows) x key-half (w>>2).
//  h=0 waves consume even tiles, h=1 odd tiles of co-staged tile PAIRS.
//  K/V LDS reads per q-row halve; 4096 waves total (16/CU) kept; partial
//  O/l summed across halves via one-time LDS exchange in the epilogue
//  (shift-free softmax partials are exactly additive - verified in R8).
//  LDS = exactly 64KB: K pair-slots dbuf 32K + V pair single-buf 16K
//  (staged at superstep top, ready by mid-barrier) + sP 16K (sequential
//  between groups; per-wave DS is in-order so B-writes follow A-reads).
//  V fragments read once into regs, used by both groups' PV.
//  Carries: shift-free softmax, sbfe mask, cvt_pk, swizzled images,
//  l=mfma(P,ones), setprio, T1 XCD remap, pack_all. R2 fallback kept.

#define B_ 2
#define H_ 16
#define S_ 2048
#define D_ 64
#define BQ 128
#define BK 64
#define NT (S_ / BK)          // 32 tiles
#define NS (NT / 2)           // 16 supersteps (tile pairs)
#define PADW 72               // fallback sP row stride
#define TILEB (BK * D_ * 2)   // 8192 bytes per bf16 tile

typedef __attribute__((ext_vector_type(4))) float f32x4;
typedef __attribute__((ext_vector_type(8))) short bf16x8;
typedef __attribute__((ext_vector_type(4))) short bf16x4;

#define QSCALE 0.1803368801111137f       // 0.125 * log2(e)
#define MASKNEG (-1.4426950408889634e9f) // -1e9 * log2(e)

static __device__ __forceinline__ short f2bf(float f) {
  __hip_bfloat16 h = __float2bfloat16(f);
  short s; __builtin_memcpy(&s, &h, sizeof(s)); return s;
}
static __device__ __forceinline__ float fexp2(float x) {
  return __builtin_amdgcn_exp2f(x);
}
static __device__ __forceinline__ unsigned cvt_pk_bf16(float a, float b) {
  unsigned r;   // r.lo = bf16(a), r.hi = bf16(b)
  asm("v_cvt_pk_bf16_f32 %0, %1, %2" : "=v"(r) : "v"(a), "v"(b));
  return r;
}
static __device__ __forceinline__ void gload_lds16(const void* g, void* l) {
  __builtin_amdgcn_global_load_lds(
      (__attribute__((address_space(1))) void*)g,
      (__attribute__((address_space(3))) void*)l, 16, 0, 0);
}

// ---------------- fused pre-pass ----------------
// blocks [0,1024): K/V -> bf16 swizzled tile images
// blocks [1024,2048): mask -> component-major bitmask
__global__ __launch_bounds__(256)
void pack_all(const float* __restrict__ kg, const float* __restrict__ vg,
              const int* __restrict__ mg,
              short* __restrict__ kw, short* __restrict__ vw,
              unsigned long long* __restrict__ mwp) {
  __shared__ float sv[BK][D_ + 1];
  const int bx  = blockIdx.x;
  const int tid = threadIdx.x;

  if (bx < 1024) {
    const int t  = bx & 31;
    const int bh = bx >> 5;
    const float* kt = kg + ((size_t)bh * S_ + t * BK) * D_;
    const float* vt = vg + ((size_t)bh * S_ + t * BK) * D_;
    short* ko = kw + ((size_t)bh * NT + t) * (BK * D_);
    short* vo = vw + ((size_t)bh * NT + t) * (BK * D_);

    const int row = tid >> 2;            // 0..63
    const int swz = (row & 7) << 4;

    // K: out byte x of row holds element d = (x ^ swz)/2
    #pragma unroll
    for (int c = 0; c < 2; ++c) {
      const int x = (tid & 3) * 32 + c * 16;
      const int dsrc = (x ^ swz) >> 1;
      const float4 u0 = *(const float4*)(kt + row * D_ + dsrc);
      const float4 u1 = *(const float4*)(kt + row * D_ + dsrc + 4);
      uint4 w;
      w.x = cvt_pk_bf16(u0.x, u0.y); w.y = cvt_pk_bf16(u0.z, u0.w);
      w.z = cvt_pk_bf16(u1.x, u1.y); w.w = cvt_pk_bf16(u1.z, u1.w);
      *(uint4*)(ko + row * D_ + (x >> 1)) = w;
    }

    // V: stage fp32 in LDS, emit transposed+swizzled
    #pragma unroll
    for (int i = 0; i < 4; ++i) {
      const int id = tid + 256 * i;
      const int r = id >> 4, c4 = (id & 15) * 4;
      const float4 u = *(const float4*)(vt + r * D_ + c4);
      sv[r][c4] = u.x; sv[r][c4+1] = u.y; sv[r][c4+2] = u.z; sv[r][c4+3] = u.w;
    }
    __syncthreads();
    #pragma unroll
    for (int c = 0; c < 2; ++c) {
      const int x = (tid & 3) * 32 + c * 16;
      const int ksrc = (x ^ swz) >> 1;
      uint4 w;
      w.x = cvt_pk_bf16(sv[ksrc+0][row], sv[ksrc+1][row]);
      w.y = cvt_pk_bf16(sv[ksrc+2][row], sv[ksrc+3][row]);
      w.z = cvt_pk_bf16(sv[ksrc+4][row], sv[ksrc+5][row]);
      w.w = cvt_pk_bf16(sv[ksrc+6][row], sv[ksrc+7][row]);
      *(uint4*)(vo + row * D_ + (x >> 1)) = w;
    }
  } else {
    // mask: component-major bit order. u64 for (row, tile):
    // bit(16*(k%4) + (k/4)%16) = mask[row][tile*64 + k]
    const int r4   = bx - 1024;
    const int wv   = tid >> 6;
    const int lane = tid & 63;
    const int row  = r4 * 4 + wv;           // 0..4095
    const int* mr = mg + (size_t)row * S_;
    unsigned long long* out = mwp + (size_t)row * NT;
    #pragma unroll
    for (int g = 0; g < 8; ++g) {
      const int4 v = *(const int4*)(mr + g * 256 + lane * 4);
      const unsigned long long b0 = __ballot(v.x != 0);
      const unsigned long long b1 = __ballot(v.y != 0);
      const unsigned long long b2 = __ballot(v.z != 0);
      const unsigned long long b3 = __ballot(v.w != 0);
      if (lane < 4) {
        const int tl = lane;
        const unsigned long long u =
            ((b0 >> (16 * tl)) & 0xFFFFULL)
          | (((b1 >> (16 * tl)) & 0xFFFFULL) << 16)
          | (((b2 >> (16 * tl)) & 0xFFFFULL) << 32)
          | (((b3 >> (16 * tl)) & 0xFFFFULL) << 48);
        out[g * 4 + tl] = u;
      }
    }
  }
}

// P = exp2(st): mask via sbfe, pack via cvt_pk, write swizzled sP.
// No row-sum (l comes from mfma(P, ones)).
static __device__ __forceinline__ void softmax_group_ns(
    const f32x4* st, unsigned long long m64, int quad, char* spg,
    int l15, int swz) {
  const unsigned xlo = ((unsigned)m64) >> quad;
  const unsigned xhi = ((unsigned)(m64 >> 32)) >> quad;
  #pragma unroll
  for (int mt = 0; mt < 4; ++mt) {
    float p0 = fexp2(st[mt].x);
    float p1 = fexp2(st[mt].y);
    float p2 = fexp2(st[mt].z);
    float p3 = fexp2(st[mt].w);
    // component-major bits: r0 -> xlo bit mt*4, r1 -> xlo bit mt*4+16,
    //                       r2 -> xhi bit mt*4, r3 -> xhi bit mt*4+16
    const int a0 = __builtin_amdgcn_sbfe((int)xlo, mt*4,      1);
    const int a1 = __builtin_amdgcn_sbfe((int)xlo, mt*4 + 16, 1);
    const int a2 = __builtin_amdgcn_sbfe((int)xhi, mt*4,      1);
    const int a3 = __builtin_amdgcn_sbfe((int)xhi, mt*4 + 16, 1);
    p0 = __uint_as_float(__float_as_uint(p0) & (unsigned)a0);
    p1 = __uint_as_float(__float_as_uint(p1) & (unsigned)a1);
    p2 = __uint_as_float(__float_as_uint(p2) & (unsigned)a2);
    p3 = __uint_as_float(__float_as_uint(p3) & (unsigned)a3);
    uint2 uu;
    uu.x = cvt_pk_bf16(p0, p1);
    uu.y = cvt_pk_bf16(p2, p3);
    *(uint2*)(spg + l15*128 + ((mt*32 + quad*8) ^ swz)) = uu;
  }
}

// ---------------- main kernel ----------------
__global__ __launch_bounds__(512, 4)
void attn_main(const float* __restrict__ qg, const short* __restrict__ kw,
               const short* __restrict__ vw,
               const unsigned long long* __restrict__ mw,
               float* __restrict__ outg) {
  __shared__ short sK2[2][2][BK * D_];   // K pair-slots, double-buffered 32 KB
  __shared__ short sV[2][BK * D_];       // current pair's V, 16 KB
  __shared__ short sP[8][16][64];        // per-wave P (seq A/B), 16 KB

  const int tid  = threadIdx.x;
  const int lane = tid & 63;
  const int wv   = tid >> 6;             // 0..7
  const int l15  = lane & 15;
  const int quad = lane >> 4;
  const int g    = wv & 3;               // q-group (32 rows)
  const int h    = wv >> 2;              // key half: even(0)/odd(1) tiles

  // T1: XCD-aware remap — 4 contiguous heads per XCD (K+V bf16 = 2MB <= L2)
  const int f  = blockIdx.y * 16 + blockIdx.x;       // 0..511
  const int nf = (f & 7) * 64 + (f >> 3);
  const int bh = nf >> 4;
  const int b  = bh >> 4;
  const int q0 = (nf & 15) * BQ;
  const int qw0 = q0 + g * 32 + l15;     // subgroup-A stats row
  const int qw1 = qw0 + 16;              // subgroup-B stats row

  // ---- Q fragments, both subgroups ----
  bf16x8 qf[2][2];
  #pragma unroll
  for (int gr = 0; gr < 2; ++gr) {
    const float* qrow = qg + ((size_t)bh * S_ + (gr ? qw1 : qw0)) * D_;
    #pragma unroll
    for (int ks = 0; ks < 2; ++ks) {
      const float4 u0 = *(const float4*)(qrow + ks*32 + quad*8);
      const float4 u1 = *(const float4*)(qrow + ks*32 + quad*8 + 4);
      bf16x8 fq;
      fq[0]=f2bf(u0.x*QSCALE); fq[1]=f2bf(u0.y*QSCALE);
      fq[2]=f2bf(u0.z*QSCALE); fq[3]=f2bf(u0.w*QSCALE);
      fq[4]=f2bf(u1.x*QSCALE); fq[5]=f2bf(u1.y*QSCALE);
      fq[6]=f2bf(u1.z*QSCALE); fq[7]=f2bf(u1.w*QSCALE);
      qf[gr][ks] = fq;
    }
  }

  bf16x8 onesf;
  #pragma unroll
  for (int j = 0; j < 8; ++j) onesf[j] = (short)0x3F80;

  f32x4 O0[4], O1[4];
  #pragma unroll
  for (int dt = 0; dt < 4; ++dt) {
    O0[dt] = (f32x4){0.f, 0.f, 0.f, 0.f};
    O1[dt] = (f32x4){0.f, 0.f, 0.f, 0.f};
  }
  f32x4 Ol0 = (f32x4){0.f, 0.f, 0.f, 0.f};
  f32x4 Ol1 = (f32x4){0.f, 0.f, 0.f, 0.f};

  const char* ktb = (const char*)(kw + (size_t)bh * NT * BK * D_);
  const char* vtb = (const char*)(vw + (size_t)bh * NT * BK * D_);
  const unsigned long long* mb0 = mw + ((size_t)b * S_ + qw0) * NT;
  const unsigned long long* mb1 = mb0 + (size_t)16 * NT;
  const int so = tid * 16;               // 512 thr x 16B = one 8KB image

  const int swz = (l15 & 7) << 4;
  const int ro0 = l15*128 + (( 0 + quad*16) ^ swz);
  const int ro1 = l15*128 + ((64 + quad*16) ^ swz);
  char* const spw = (char*)sP + wv*2048;

  // ---- prologue: stage K pair 0 (tiles 0,1) into slot 0 ----
  gload_lds16(ktb + so,         (char*)sK2 + so);
  gload_lds16(ktb + TILEB + so, (char*)sK2 + 8192 + so);
  const char* kp = ktb + 2 * TILEB;      // next K pair to stage
  const char* vs = vtb;                  // this superstep's V pair
  __syncthreads();

  for (int s = 0; s < NS; ++s) {
    // ---- stage V(pair s) now (ready by mid-barrier, after QK+softmax) ----
    gload_lds16(vs + so,         (char*)sV + so);
    gload_lds16(vs + TILEB + so, (char*)sV + 8192 + so);
    vs += 2 * TILEB;
    // ---- prefetch K(pair s+1) into the other slot ----
    if (s < NS - 1) {
      char* dst = (char*)sK2 + ((s + 1) & 1) * 16384;
      gload_lds16(kp + so,         dst + so);
      gload_lds16(kp + TILEB + so, dst + 8192 + so);
      kp += 2 * TILEB;
    }
    const unsigned long long m64a = mb0[2*s + h];
    const unsigned long long m64b = mb1[2*s + h];
    const char* kb = (const char*)sK2 + (s & 1) * 16384 + h * 8192;
    const char* vb = (const char*)sV + h * 8192;

    // ---- S^T = K * Q^T, both subgroups share the K fragment reads ----
    f32x4 st0[4], st1[4];
    __builtin_amdgcn_s_setprio(1);
    #pragma unroll
    for (int mt = 0; mt < 4; ++mt) {
      const bf16x8 kf0 = *(const bf16x8*)(kb + mt*2048 + ro0);
      const bf16x8 kf1 = *(const bf16x8*)(kb + mt*2048 + ro1);
      f32x4 a0 = (f32x4){0.f, 0.f, 0.f, 0.f};
      f32x4 a1 = (f32x4){0.f, 0.f, 0.f, 0.f};
      a0 = __builtin_amdgcn_mfma_f32_16x16x32_bf16(kf0, qf[0][0], a0, 0, 0, 0);
      a1 = __builtin_amdgcn_mfma_f32_16x16x32_bf16(kf0, qf[1][0], a1, 0, 0, 0);
      a0 = __builtin_amdgcn_mfma_f32_16x16x32_bf16(kf1, qf[0][1], a0, 0, 0, 0);
      a1 = __builtin_amdgcn_mfma_f32_16x16x32_bf16(kf1, qf[1][1], a1, 0, 0, 0);
      st0[mt] = a0; st1[mt] = a1;
    }
    __builtin_amdgcn_s_setprio(0);

    // ---- softmax A -> sP; read A's P-frags; softmax B -> sP (in-order DS:
    //      B's writes cannot pass A's earlier reads of the same region) ----
    softmax_group_ns(st0, m64a, quad, spw, l15, swz);
    asm volatile("s_waitcnt lgkmcnt(0)" ::: "memory");
    const bf16x8 pfA0 = *(const bf16x8*)(spw + l15*128 + (( 0 + quad*16) ^ swz));
    const bf16x8 pfA1 = *(const bf16x8*)(spw + l15*128 + ((64 + quad*16) ^ swz));
    softmax_group_ns(st1, m64b, quad, spw, l15, swz);

    __syncthreads();   // V(pair s) landed for all waves

    // ---- PV-A: V fragments into regs (kept for PV-B) ----
    bf16x8 vf0[4], vf1[4];
    __builtin_amdgcn_s_setprio(1);
    #pragma unroll
    for (int dt = 0; dt < 4; ++dt) {
      vf0[dt] = *(const bf16x8*)(vb + dt*2048 + ro0);
      vf1[dt] = *(const bf16x8*)(vb + dt*2048 + ro1);
      O0[dt] = __builtin_amdgcn_mfma_f32_16x16x32_bf16(pfA0, vf0[dt], O0[dt], 0, 0, 0);
      O0[dt] = __builtin_amdgcn_mfma_f32_16x16x32_bf16(pfA1, vf1[dt], O0[dt], 0, 0, 0);
    }
    Ol0 = __builtin_amdgcn_mfma_f32_16x16x32_bf16(pfA0, onesf, Ol0, 0, 0, 0);
    Ol0 = __builtin_amdgcn_mfma_f32_16x16x32_bf16(pfA1, onesf, Ol0, 0, 0, 0);
    __builtin_amdgcn_s_setprio(0);

    // ---- PV-B: P-frags from sP (B's writes), V from regs ----
    asm volatile("s_waitcnt lgkmcnt(0)" ::: "memory");
    const bf16x8 pfB0 = *(const bf16x8*)(spw + l15*128 + (( 0 + quad*16) ^ swz));
    const bf16x8 pfB1 = *(const bf16x8*)(spw + l15*128 + ((64 + quad*16) ^ swz));
    __builtin_amdgcn_s_setprio(1);
    #pragma unroll
    for (int dt = 0; dt < 4; ++dt) {
      O1[dt] = __builtin_amdgcn_mfma_f32_16x16x32_bf16(pfB0, vf0[dt], O1[dt], 0, 0, 0);
      O1[dt] = __builtin_amdgcn_mfma_f32_16x16x32_bf16(pfB1, vf1[dt], O1[dt], 0, 0, 0);
    }
    Ol1 = __builtin_amdgcn_mfma_f32_16x16x32_bf16(pfB0, onesf, Ol1, 0, 0, 0);
    Ol1 = __builtin_amdgcn_mfma_f32_16x16x32_bf16(pfB1, onesf, Ol1, 0, 0, 0);
    __builtin_amdgcn_s_setprio(0);

    __syncthreads();   // V reads done -> sV reusable; K(s+1) landed
  }

  // ---- epilogue: sum the two key-halves via LDS, normalize, store ----
  // (loop ended with a barrier; sK2/sV are free for reuse)
  const int exsw = (lane & 7) << 4;
  if (h == 1) {
    char* eb = (char*)sK2 + g * 8192 + lane * 128;
    #pragma unroll
    for (int dt = 0; dt < 4; ++dt) {
      *(f32x4*)(eb + ((dt*16) ^ exsw))       = O0[dt];
      *(f32x4*)(eb + (((dt+4)*16) ^ exsw))   = O1[dt];
    }
    *(f32x4*)((char*)sV + g*4096 + lane*32)      = Ol0;
    *(f32x4*)((char*)sV + g*4096 + lane*32 + 16) = Ol1;
  }
  __syncthreads();
  if (h == 0) {
    const char* eb = (const char*)sK2 + g * 8192 + lane * 128;
    Ol0 += *(const f32x4*)((const char*)sV + g*4096 + lane*32);
    Ol1 += *(const f32x4*)((const char*)sV + g*4096 + lane*32 + 16);
    #pragma unroll
    for (int dt = 0; dt < 4; ++dt) {
      O0[dt] += *(const f32x4*)(eb + ((dt*16) ^ exsw));
      O1[dt] += *(const f32x4*)(eb + (((dt+4)*16) ^ exsw));
    }
    float ira[4], irb[4];
    ira[0] = 1.0f / Ol0.x; ira[1] = 1.0f / Ol0.y;
    ira[2] = 1.0f / Ol0.z; ira[3] = 1.0f / Ol0.w;
    irb[0] = 1.0f / Ol1.x; irb[1] = 1.0f / Ol1.y;
    irb[2] = 1.0f / Ol1.z; irb[3] = 1.0f / Ol1.w;

    float* ob0 = outg + ((size_t)bh * S_ + q0 + g*32) * D_;
    float* ob1 = ob0 + 16 * D_;
    #pragma unroll
    for (int dt = 0; dt < 4; ++dt) {
      ob0[(quad*4 + 0)*D_ + dt*16 + l15] = O0[dt].x * ira[0];
      ob0[(quad*4 + 1)*D_ + dt*16 + l15] = O0[dt].y * ira[1];
      ob0[(quad*4 + 2)*D_ + dt*16 + l15] = O0[dt].z * ira[2];
      ob0[(quad*4 + 3)*D_ + dt*16 + l15] = O0[dt].w * ira[3];
      ob1[(quad*4 + 0)*D_ + dt*16 + l15] = O1[dt].x * irb[0];
      ob1[(quad*4 + 1)*D_ + dt*16 + l15] = O1[dt].y * irb[1];
      ob1[(quad*4 + 2)*D_ + dt*16 + l15] = O1[dt].z * irb[2];
      ob1[(quad*4 + 3)*D_ + dt*16 + l15] = O1[dt].w * irb[3];
    }
  }
}

// ---------------- fallback: verified R2 kernel (used if ws tiny) ------------
__global__ __launch_bounds__(256, 4)
void attn_fallback(const float* __restrict__ qg, const float* __restrict__ kg,
                   const float* __restrict__ vg, const int* __restrict__ maskg,
                   float* __restrict__ outg) {
  __shared__ short sK[BK][PADW];
  __shared__ short sVT[D_][PADW];
  __shared__ short sP[4][16][PADW];

  const int tid  = threadIdx.x;
  const int lane = tid & 63;
  const int wv   = tid >> 6;
  const int l15  = lane & 15;
  const int quad = lane >> 4;

  const int bh = blockIdx.y;
  const int b  = bh >> 4;
  const int q0 = blockIdx.x * 64;
  const int qw = q0 + wv * 16 + l15;

  bf16x8 qf[2];
  {
    const float* qrow = qg + ((size_t)bh * S_ + qw) * D_;
    #pragma unroll
    for (int ks = 0; ks < 2; ++ks) {
      const float4 u0 = *(const float4*)(qrow + ks*32 + quad*8);
      const float4 u1 = *(const float4*)(qrow + ks*32 + quad*8 + 4);
      bf16x8 fq;
      fq[0]=f2bf(u0.x*QSCALE); fq[1]=f2bf(u0.y*QSCALE);
      fq[2]=f2bf(u0.z*QSCALE); fq[3]=f2bf(u0.w*QSCALE);
      fq[4]=f2bf(u1.x*QSCALE); fq[5]=f2bf(u1.y*QSCALE);
      fq[6]=f2bf(u1.z*QSCALE); fq[7]=f2bf(u1.w*QSCALE);
      qf[ks] = fq;
    }
  }

  f32x4 O[4];
  #pragma unroll
  for (int dt = 0; dt < 4; ++dt) O[dt] = (f32x4){0.f, 0.f, 0.f, 0.f};
  float m = -3.0e38f, l = 0.f;

  const float* kbase = kg + (size_t)bh * S_ * D_;
  const float* vbase = vg + (size_t)bh * S_ * D_;
  const int*   mrow  = maskg + ((size_t)b * S_ + qw) * S_;

  for (int t0 = 0; t0 < S_; t0 += BK) {
    __syncthreads();
    #pragma unroll
    for (int i = 0; i < 4; ++i) {
      const int id = tid + 256*i;
      const int key = id >> 4, d4 = (id & 15) * 4;
      const float4 u = *(const float4*)(kbase + (size_t)(t0 + key)*D_ + d4);
      bf16x4 w; w[0]=f2bf(u.x); w[1]=f2bf(u.y); w[2]=f2bf(u.z); w[3]=f2bf(u.w);
      *(bf16x4*)&sK[key][d4] = w;
    }
    #pragma unroll
    for (int i = 0; i < 2; ++i) {
      const int id = tid + 256*i;
      const int kp = id & 31, d4 = (id >> 5) * 4;
      const float4 a = *(const float4*)(vbase + (size_t)(t0 + 2*kp    )*D_ + d4);
      const float4 c = *(const float4*)(vbase + (size_t)(t0 + 2*kp + 1)*D_ + d4);
      const float av[4] = {a.x, a.y, a.z, a.w};
      const float cv[4] = {c.x, c.y, c.z, c.w};
      #pragma unroll
      for (int j = 0; j < 4; ++j) {
        const unsigned pk = (unsigned)(unsigned short)f2bf(av[j])
                          | ((unsigned)(unsigned short)f2bf(cv[j]) << 16);
        *(unsigned*)&sVT[d4 + j][2*kp] = pk;
      }
    }
    __syncthreads();

    int4 mk[4];
    #pragma unroll
    for (int mt = 0; mt < 4; ++mt)
      mk[mt] = *(const int4*)(mrow + t0 + mt*16 + quad*4);

    f32x4 st[4];
    #pragma unroll
    for (int mt = 0; mt < 4; ++mt) {
      f32x4 acc = (f32x4){0.f, 0.f, 0.f, 0.f};
      #pragma unroll
      for (int ks = 0; ks < 2; ++ks) {
        const bf16x8 kf = *(const bf16x8*)&sK[mt*16 + l15][ks*32 + quad*8];
        acc = __builtin_amdgcn_mfma_f32_16x16x32_bf16(kf, qf[ks], acc, 0, 0, 0);
      }
      st[mt] = acc;
    }

    float cmax = -3.0e38f;
    #pragma unroll
    for (int mt = 0; mt < 4; ++mt) {
      f32x4 s = st[mt];
      s.x = mk[mt].x ? s.x : MASKNEG;
      s.y = mk[mt].y ? s.y : MASKNEG;
      s.z = mk[mt].z ? s.z : MASKNEG;
      s.w = mk[mt].w ? s.w : MASKNEG;
      st[mt] = s;
      cmax = fmaxf(cmax, fmaxf(fmaxf(s.x, s.y), fmaxf(s.z, s.w)));
    }
    cmax = fmaxf(cmax, __shfl_xor(cmax, 16));
    cmax = fmaxf(cmax, __shfl_xor(cmax, 32));
    const float mnew  = fmaxf(m, cmax);
    const float alpha = fexp2(m - mnew);
    m = mnew;

    float lsum = 0.f;
    #pragma unroll
    for (int mt = 0; mt < 4; ++mt) {
      const float p0 = fexp2(st[mt].x - mnew);
      const float p1 = fexp2(st[mt].y - mnew);
      const float p2 = fexp2(st[mt].z - mnew);
      const float p3 = fexp2(st[mt].w - mnew);
      lsum += (p0 + p1) + (p2 + p3);
      bf16x4 pw; pw[0]=f2bf(p0); pw[1]=f2bf(p1); pw[2]=f2bf(p2); pw[3]=f2bf(p3);
      *(bf16x4*)&sP[wv][l15][mt*16 + quad*4] = pw;
    }
    lsum += __shfl_xor(lsum, 16);
    lsum += __shfl_xor(lsum, 32);
    l = l * alpha + lsum;

    const float ar0 = __shfl(alpha, quad*4 + 0);
    const float ar1 = __shfl(alpha, quad*4 + 1);
    const float ar2 = __shfl(alpha, quad*4 + 2);
    const float ar3 = __shfl(alpha, quad*4 + 3);
    #pragma unroll
    for (int dt = 0; dt < 4; ++dt) {
      O[dt].x *= ar0; O[dt].y *= ar1; O[dt].z *= ar2; O[dt].w *= ar3;
    }

    asm volatile("s_waitcnt lgkmcnt(0)" ::: "memory");

    const bf16x8 pf0 = *(const bf16x8*)&sP[wv][l15][quad*8];
    const bf16x8 pf1 = *(const bf16x8*)&sP[wv][l15][32 + quad*8];
    #pragma unroll
    for (int dt = 0; dt < 4; ++dt) {
      const bf16x8 vf0 = *(const bf16x8*)&sVT[dt*16 + l15][quad*8];
      const bf16x8 vf1 = *(const bf16x8*)&sVT[dt*16 + l15][32 + quad*8];
      O[dt] = __builtin_amdgcn_mfma_f32_16x16x32_bf16(pf0, vf0, O[dt], 0, 0, 0);
      O[dt] = __builtin_amdgcn_mfma_f32_16x16x32_bf16(pf1, vf1, O[dt], 0, 0, 0);
    }
  }

  float ir[4];
  #pragma unroll
  for (int r = 0; r < 4; ++r) ir[r] = 1.0f / __shfl(l, quad*4 + r);

  float* ob = outg + ((size_t)bh * S_ + q0 + wv*16) * D_;
  #pragma unroll
  for (int dt = 0; dt < 4; ++dt) {
    ob[(quad*4 + 0)*D_ + dt*16 + l15] = O[dt].x * ir[0];
    ob[(quad*4 + 1)*D_ + dt*16 + l15] = O[dt].y * ir[1];
    ob[(quad*4 + 2)*D_ + dt*16 + l15] = O[dt].z * ir[2];
    ob[(quad*4 + 3)*D_ + dt*16 + l15] = O[dt].w * ir[3];
  }
}

extern "C" void kernel_launch(void* const* d_in, const int* in_sizes, int n_in,
                              void* d_out, int out_size, void* d_ws, size_t ws_size,
                              hipStream_t stream) {
  const float* q    = (const float*)d_in[0];
  const float* k    = (const float*)d_in[1];
  const float* v    = (const float*)d_in[2];
  const int*   mask = (const int*)d_in[3];
  float* out = (float*)d_out;

  const size_t kvbytes = (size_t)B_ * H_ * S_ * D_ * 2;          // 8 MB each
  const size_t mbytes  = (size_t)B_ * S_ * NT * 8;               // 1 MB
  const size_t need    = 2 * kvbytes + mbytes;

  if (d_ws != nullptr && ws_size >= need) {
    short* kwp = (short*)d_ws;
    short* vwp = (short*)((char*)d_ws + kvbytes);
    unsigned long long* mwp = (unsigned long long*)((char*)d_ws + 2 * kvbytes);
    pack_all<<<dim3(2048), 256, 0, stream>>>(k, v, mask, kwp, vwp, mwp);
    attn_main<<<dim3(S_ / BQ, B_ * H_), 512, 0, stream>>>(q, kwp, vwp, mwp, out);
  } else {
    attn_fallback<<<dim3(S_ / 64, B_ * H_), 256, 0, stream>>>(q, k, v, mask, out);
  }
}

// Round 9
// 169.495 us; speedup vs baseline: 1.0392x; 1.0392x over previous
//
#include <hip/hip_runtime.h>
#include <hip/hip_bf16.h>

// DotProductAttention B=2,H=16,S=2048,D=64 fp32 in/out, int32 mask (B,1,S,S).
// R11: in-register P transpose (T12 generalized) — sP LDS round-trip deleted.
//  QK's C-layout st (lane: P[key=quad*4+r][q=l15]) is converted to PV's
//  A-layout (lane: P[q=l15][key=quad*8+j]) with 8 cvt_pk + 8 permlane ops:
//  each (U[2i].w, U[2i+1].w) pair -> one v_permlane32_swap_b32 + one
//  v_permlane16_swap_b32 yields two pf words directly (derivation in-line).
//  Removes 4 ds_write_b64 + lgkmcnt(0) drain + 2 ds_read_b128 per wave-tile
//  AND frees 16KB LDS: block LDS = 32KB (K/V dbuf) -> 4 blocks/CU at
//  __launch_bounds__(512,8) = 32 waves/CU (2x R9's TLP; R7/R10 showed TLP
//  loss is fatal). Loop = R5's proven 2-phase double-buffer, 1 barrier/tile
//  (R9 A/B: counted-vmcnt == drain here). Carries: shift-free softmax
//  (|st|<=~8 << 128 fp32 exp2 limit; shift-invariant), sbfe mask,
//  l=mfma(P,ones) (rows align with O; no epilogue shuffles), setprio,
//  T1 XCD remap, pack_all pre-pass. R2 fallback kept.

#define B_ 2
#define H_ 16
#define S_ 2048
#define D_ 64
#define BQ 128
#define BK 64
#define NT (S_ / BK)          // 32 tiles
#define PADW 72               // fallback sP row stride
#define TILEB (BK * D_ * 2)   // 8192 bytes per bf16 tile

typedef __attribute__((ext_vector_type(4))) float f32x4;
typedef __attribute__((ext_vector_type(8))) short bf16x8;
typedef __attribute__((ext_vector_type(4))) short bf16x4;
typedef __attribute__((ext_vector_type(4))) unsigned u32x4;

#define QSCALE 0.1803368801111137f       // 0.125 * log2(e)
#define MASKNEG (-1.4426950408889634e9f) // -1e9 * log2(e)

static __device__ __forceinline__ short f2bf(float f) {
  __hip_bfloat16 h = __float2bfloat16(f);
  short s; __builtin_memcpy(&s, &h, sizeof(s)); return s;
}
static __device__ __forceinline__ float fexp2(float x) {
  return __builtin_amdgcn_exp2f(x);
}
static __device__ __forceinline__ unsigned cvt_pk_bf16(float a, float b) {
  unsigned r;   // r.lo = bf16(a), r.hi = bf16(b)
  asm("v_cvt_pk_bf16_f32 %0, %1, %2" : "=v"(r) : "v"(a), "v"(b));
  return r;
}
static __device__ __forceinline__ void gload_lds16(const void* g, void* l) {
  __builtin_amdgcn_global_load_lds(
      (__attribute__((address_space(1))) void*)g,
      (__attribute__((address_space(3))) void*)l, 16, 0, 0);
}
// swap lanes 32-63 of a with lanes 0-31 of b: a'=[aLo,bLo], b'=[aHi,bHi]
static __device__ __forceinline__ void perm32sw(unsigned& a, unsigned& b) {
  asm("v_permlane32_swap_b32 %0, %1" : "+v"(a), "+v"(b));
}
// swap 16-lane rows: a'=[a0,b0,a2,b2], b'=[a1,b1,a3,b3]
static __device__ __forceinline__ void perm16sw(unsigned& a, unsigned& b) {
  asm("v_permlane16_swap_b32 %0, %1" : "+v"(a), "+v"(b));
}

// ---------------- fused pre-pass ----------------
// blocks [0,1024): K/V -> bf16 swizzled tile images
// blocks [1024,2048): mask -> component-major bitmask
__global__ __launch_bounds__(256)
void pack_all(const float* __restrict__ kg, const float* __restrict__ vg,
              const int* __restrict__ mg,
              short* __restrict__ kw, short* __restrict__ vw,
              unsigned long long* __restrict__ mwp) {
  __shared__ float sv[BK][D_ + 1];
  const int bx  = blockIdx.x;
  const int tid = threadIdx.x;

  if (bx < 1024) {
    const int t  = bx & 31;
    const int bh = bx >> 5;
    const float* kt = kg + ((size_t)bh * S_ + t * BK) * D_;
    const float* vt = vg + ((size_t)bh * S_ + t * BK) * D_;
    short* ko = kw + ((size_t)bh * NT + t) * (BK * D_);
    short* vo = vw + ((size_t)bh * NT + t) * (BK * D_);

    const int row = tid >> 2;            // 0..63
    const int swz = (row & 7) << 4;

    // K: out byte x of row holds element d = (x ^ swz)/2
    #pragma unroll
    for (int c = 0; c < 2; ++c) {
      const int x = (tid & 3) * 32 + c * 16;
      const int dsrc = (x ^ swz) >> 1;
      const float4 u0 = *(const float4*)(kt + row * D_ + dsrc);
      const float4 u1 = *(const float4*)(kt + row * D_ + dsrc + 4);
      uint4 w;
      w.x = cvt_pk_bf16(u0.x, u0.y); w.y = cvt_pk_bf16(u0.z, u0.w);
      w.z = cvt_pk_bf16(u1.x, u1.y); w.w = cvt_pk_bf16(u1.z, u1.w);
      *(uint4*)(ko + row * D_ + (x >> 1)) = w;
    }

    // V: stage fp32 in LDS, emit transposed+swizzled
    #pragma unroll
    for (int i = 0; i < 4; ++i) {
      const int id = tid + 256 * i;
      const int r = id >> 4, c4 = (id & 15) * 4;
      const float4 u = *(const float4*)(vt + r * D_ + c4);
      sv[r][c4] = u.x; sv[r][c4+1] = u.y; sv[r][c4+2] = u.z; sv[r][c4+3] = u.w;
    }
    __syncthreads();
    #pragma unroll
    for (int c = 0; c < 2; ++c) {
      const int x = (tid & 3) * 32 + c * 16;
      const int ksrc = (x ^ swz) >> 1;
      uint4 w;
      w.x = cvt_pk_bf16(sv[ksrc+0][row], sv[ksrc+1][row]);
      w.y = cvt_pk_bf16(sv[ksrc+2][row], sv[ksrc+3][row]);
      w.z = cvt_pk_bf16(sv[ksrc+4][row], sv[ksrc+5][row]);
      w.w = cvt_pk_bf16(sv[ksrc+6][row], sv[ksrc+7][row]);
      *(uint4*)(vo + row * D_ + (x >> 1)) = w;
    }
  } else {
    // mask: component-major bit order. u64 for (row, tile):
    // bit(16*(k%4) + (k/4)%16) = mask[row][tile*64 + k]
    const int r4   = bx - 1024;
    const int wv   = tid >> 6;
    const int lane = tid & 63;
    const int row  = r4 * 4 + wv;           // 0..4095
    const int* mr = mg + (size_t)row * S_;
    unsigned long long* out = mwp + (size_t)row * NT;
    #pragma unroll
    for (int g = 0; g < 8; ++g) {
      const int4 v = *(const int4*)(mr + g * 256 + lane * 4);
      const unsigned long long b0 = __ballot(v.x != 0);
      const unsigned long long b1 = __ballot(v.y != 0);
      const unsigned long long b2 = __ballot(v.z != 0);
      const unsigned long long b3 = __ballot(v.w != 0);
      if (lane < 4) {
        const int tl = lane;
        const unsigned long long u =
            ((b0 >> (16 * tl)) & 0xFFFFULL)
          | (((b1 >> (16 * tl)) & 0xFFFFULL) << 16)
          | (((b2 >> (16 * tl)) & 0xFFFFULL) << 32)
          | (((b3 >> (16 * tl)) & 0xFFFFULL) << 48);
        out[g * 4 + tl] = u;
      }
    }
  }
}

// ---------------- main kernel ----------------
__global__ __launch_bounds__(512, 8)
void attn_main(const float* __restrict__ qg, const short* __restrict__ kw,
               const short* __restrict__ vw,
               const unsigned long long* __restrict__ mw,
               float* __restrict__ outg) {
  __shared__ short sKV[2][2][BK * D_];   // [buf][K,V][4096] = 32 KB (all LDS)

  const int tid  = threadIdx.x;
  const int lane = tid & 63;
  const int wv   = tid >> 6;             // 0..7
  const int l15  = lane & 15;
  const int quad = lane >> 4;

  // T1: XCD-aware remap — 4 contiguous heads per XCD (K+V bf16 = 2MB <= L2)
  const int f  = blockIdx.y * 16 + blockIdx.x;       // 0..511
  const int nf = (f & 7) * 64 + (f >> 3);
  const int bh = nf >> 4;
  const int b  = bh >> 4;
  const int q0 = (nf & 15) * BQ;
  const int qw = q0 + wv * 16 + l15;   // this lane's stats-query row

  // ---- Q fragments (B-operand: lane holds Q[q=l15][d=ks*32+quad*8+j]) ----
  bf16x8 qf[2];
  {
    const float* qrow = qg + ((size_t)bh * S_ + qw) * D_;
    #pragma unroll
    for (int ks = 0; ks < 2; ++ks) {
      const float4 u0 = *(const float4*)(qrow + ks*32 + quad*8);
      const float4 u1 = *(const float4*)(qrow + ks*32 + quad*8 + 4);
      bf16x8 fq;
      fq[0]=f2bf(u0.x*QSCALE); fq[1]=f2bf(u0.y*QSCALE);
      fq[2]=f2bf(u0.z*QSCALE); fq[3]=f2bf(u0.w*QSCALE);
      fq[4]=f2bf(u1.x*QSCALE); fq[5]=f2bf(u1.y*QSCALE);
      fq[6]=f2bf(u1.z*QSCALE); fq[7]=f2bf(u1.w*QSCALE);
      qf[ks] = fq;
    }
  }

  // ones B-fragment: l = mfma(P, ones) — rows align with O's rows.
  bf16x8 onesf;
  #pragma unroll
  for (int j = 0; j < 8; ++j) onesf[j] = (short)0x3F80;

  f32x4 O[4];
  #pragma unroll
  for (int dt = 0; dt < 4; ++dt) O[dt] = (f32x4){0.f, 0.f, 0.f, 0.f};
  f32x4 Ol = (f32x4){0.f, 0.f, 0.f, 0.f};

  const char* kt = (const char*)(kw + (size_t)bh * NT * BK * D_);
  const char* vt = (const char*)(vw + (size_t)bh * NT * BK * D_);
  const unsigned long long* mb = mw + ((size_t)b * S_ + qw) * NT;
  const int so = tid * 16;             // 512 thr x 16B = one 8KB image

  const int swz = (l15 & 7) << 4;
  const int ro0 = l15*128 + (( 0 + quad*16) ^ swz);
  const int ro1 = l15*128 + ((64 + quad*16) ^ swz);

  // ---- prologue: stage tile 0 into buf 0 ----
  gload_lds16(kt + so, (char*)sKV + so);
  gload_lds16(vt + so, (char*)sKV + 8192 + so);
  kt += TILEB; vt += TILEB;
  int cur = 0;
  __syncthreads();

  for (int t = 0; t < NT; ++t) {
    const unsigned long long m64 = mb[t];
    // ---- prefetch next tile into the other buffer (T3 2-phase) ----
    if (t < NT - 1) {
      const int nb = (cur ^ 1) << 14;
      gload_lds16(kt + so, (char*)sKV + nb + so);
      gload_lds16(vt + so, (char*)sKV + nb + 8192 + so);
      kt += TILEB; vt += TILEB;
    }
    const char* kb = (const char*)sKV + (cur << 14);
    const char* vb = kb + 8192;

    // ---- S^T = K * Q^T : st[mt].r = P-score[key=mt*16+quad*4+r][q=l15] ----
    f32x4 st[4];
    __builtin_amdgcn_s_setprio(1);
    #pragma unroll
    for (int mt = 0; mt < 4; ++mt) {
      f32x4 acc = (f32x4){0.f, 0.f, 0.f, 0.f};
      const bf16x8 kf0 = *(const bf16x8*)(kb + mt*2048 + ro0);
      const bf16x8 kf1 = *(const bf16x8*)(kb + mt*2048 + ro1);
      acc = __builtin_amdgcn_mfma_f32_16x16x32_bf16(kf0, qf[0], acc, 0, 0, 0);
      acc = __builtin_amdgcn_mfma_f32_16x16x32_bf16(kf1, qf[1], acc, 0, 0, 0);
      st[mt] = acc;
    }
    __builtin_amdgcn_s_setprio(0);

    // ---- P = exp2(st) (shift-free), sbfe mask, pack to bf16 pairs ----
    // U[mt] = {keys mt*16+quad*4+{0,1}, mt*16+quad*4+{2,3}} for q=l15
    const unsigned xlo = ((unsigned)m64) >> quad;
    const unsigned xhi = ((unsigned)(m64 >> 32)) >> quad;
    uint2 U[4];
    #pragma unroll
    for (int mt = 0; mt < 4; ++mt) {
      float p0 = fexp2(st[mt].x);
      float p1 = fexp2(st[mt].y);
      float p2 = fexp2(st[mt].z);
      float p3 = fexp2(st[mt].w);
      const int a0 = __builtin_amdgcn_sbfe((int)xlo, mt*4,      1);
      const int a1 = __builtin_amdgcn_sbfe((int)xlo, mt*4 + 16, 1);
      const int a2 = __builtin_amdgcn_sbfe((int)xhi, mt*4,      1);
      const int a3 = __builtin_amdgcn_sbfe((int)xhi, mt*4 + 16, 1);
      p0 = __uint_as_float(__float_as_uint(p0) & (unsigned)a0);
      p1 = __uint_as_float(__float_as_uint(p1) & (unsigned)a1);
      p2 = __uint_as_float(__float_as_uint(p2) & (unsigned)a2);
      p3 = __uint_as_float(__float_as_uint(p3) & (unsigned)a3);
      U[mt].x = cvt_pk_bf16(p0, p1);
      U[mt].y = cvt_pk_bf16(p2, p3);
    }

    // ---- in-register C->A transpose: target lane (qt,l15) word w of pf0 =
    // keys qt*8+2w,+1 => tile U[qt>>1], source quad 2(qt&1)+(w>>1), word w&1.
    // perm32(a,b): a'=[aLo,bLo] b'=[aHi,bHi]; perm16: a''=[a0,b0,a2,b2],
    // b''=[a1,b1,a3,b3]. (U[2i].w,U[2i+1].w) -> pf words directly.
    unsigned w00 = U[0].x, w02 = U[1].x;   // -> pf0.w0, pf0.w2
    perm32sw(w00, w02); perm16sw(w00, w02);
    unsigned w01 = U[0].y, w03 = U[1].y;   // -> pf0.w1, pf0.w3
    perm32sw(w01, w03); perm16sw(w01, w03);
    unsigned w10 = U[2].x, w12 = U[3].x;   // -> pf1.w0, pf1.w2
    perm32sw(w10, w12); perm16sw(w10, w12);
    unsigned w11 = U[2].y, w13 = U[3].y;   // -> pf1.w1, pf1.w3
    perm32sw(w11, w13); perm16sw(w11, w13);
    bf16x8 pf0, pf1;
    {
      u32x4 t0 = (u32x4){w00, w01, w02, w03};
      u32x4 t1 = (u32x4){w10, w11, w12, w13};
      __builtin_memcpy(&pf0, &t0, 16);
      __builtin_memcpy(&pf1, &t1, 16);
    }

    // ---- O += P * V;  l += P * ones (matrix pipe) ----
    __builtin_amdgcn_s_setprio(1);
    #pragma unroll
    for (int dt = 0; dt < 4; ++dt) {
      const bf16x8 vf0 = *(const bf16x8*)(vb + dt*2048 + ro0);
      const bf16x8 vf1 = *(const bf16x8*)(vb + dt*2048 + ro1);
      O[dt] = __builtin_amdgcn_mfma_f32_16x16x32_bf16(pf0, vf0, O[dt], 0, 0, 0);
      O[dt] = __builtin_amdgcn_mfma_f32_16x16x32_bf16(pf1, vf1, O[dt], 0, 0, 0);
    }
    Ol = __builtin_amdgcn_mfma_f32_16x16x32_bf16(pf0, onesf, Ol, 0, 0, 0);
    Ol = __builtin_amdgcn_mfma_f32_16x16x32_bf16(pf1, onesf, Ol, 0, 0, 0);
    __builtin_amdgcn_s_setprio(0);

    __syncthreads();   // drains the prefetch (vmcnt 0) for next tile
    cur ^= 1;
  }

  // ---- epilogue: Ol rows align with O rows — direct normalize, store ----
  float ir[4];
  ir[0] = 1.0f / Ol.x; ir[1] = 1.0f / Ol.y;
  ir[2] = 1.0f / Ol.z; ir[3] = 1.0f / Ol.w;

  float* ob = outg + ((size_t)bh * S_ + q0 + wv*16) * D_;
  #pragma unroll
  for (int dt = 0; dt < 4; ++dt) {
    ob[(quad*4 + 0)*D_ + dt*16 + l15] = O[dt].x * ir[0];
    ob[(quad*4 + 1)*D_ + dt*16 + l15] = O[dt].y * ir[1];
    ob[(quad*4 + 2)*D_ + dt*16 + l15] = O[dt].z * ir[2];
    ob[(quad*4 + 3)*D_ + dt*16 + l15] = O[dt].w * ir[3];
  }
}

// ---------------- fallback: verified R2 kernel (used if ws tiny) ------------
__global__ __launch_bounds__(256, 4)
void attn_fallback(const float* __restrict__ qg, const float* __restrict__ kg,
                   const float* __restrict__ vg, const int* __restrict__ maskg,
                   float* __restrict__ outg) {
  __shared__ short sK[BK][PADW];
  __shared__ short sVT[D_][PADW];
  __shared__ short sP[4][16][PADW];

  const int tid  = threadIdx.x;
  const int lane = tid & 63;
  const int wv   = tid >> 6;
  const int l15  = lane & 15;
  const int quad = lane >> 4;

  const int bh = blockIdx.y;
  const int b  = bh >> 4;
  const int q0 = blockIdx.x * 64;
  const int qw = q0 + wv * 16 + l15;

  bf16x8 qf[2];
  {
    const float* qrow = qg + ((size_t)bh * S_ + qw) * D_;
    #pragma unroll
    for (int ks = 0; ks < 2; ++ks) {
      const float4 u0 = *(const float4*)(qrow + ks*32 + quad*8);
      const float4 u1 = *(const float4*)(qrow + ks*32 + quad*8 + 4);
      bf16x8 fq;
      fq[0]=f2bf(u0.x*QSCALE); fq[1]=f2bf(u0.y*QSCALE);
      fq[2]=f2bf(u0.z*QSCALE); fq[3]=f2bf(u0.w*QSCALE);
      fq[4]=f2bf(u1.x*QSCALE); fq[5]=f2bf(u1.y*QSCALE);
      fq[6]=f2bf(u1.z*QSCALE); fq[7]=f2bf(u1.w*QSCALE);
      qf[ks] = fq;
    }
  }

  f32x4 O[4];
  #pragma unroll
  for (int dt = 0; dt < 4; ++dt) O[dt] = (f32x4){0.f, 0.f, 0.f, 0.f};
  float m = -3.0e38f, l = 0.f;

  const float* kbase = kg + (size_t)bh * S_ * D_;
  const float* vbase = vg + (size_t)bh * S_ * D_;
  const int*   mrow  = maskg + ((size_t)b * S_ + qw) * S_;

  for (int t0 = 0; t0 < S_; t0 += BK) {
    __syncthreads();
    #pragma unroll
    for (int i = 0; i < 4; ++i) {
      const int id = tid + 256*i;
      const int key = id >> 4, d4 = (id & 15) * 4;
      const float4 u = *(const float4*)(kbase + (size_t)(t0 + key)*D_ + d4);
      bf16x4 w; w[0]=f2bf(u.x); w[1]=f2bf(u.y); w[2]=f2bf(u.z); w[3]=f2bf(u.w);
      *(bf16x4*)&sK[key][d4] = w;
    }
    #pragma unroll
    for (int i = 0; i < 2; ++i) {
      const int id = tid + 256*i;
      const int kp = id & 31, d4 = (id >> 5) * 4;
      const float4 a = *(const float4*)(vbase + (size_t)(t0 + 2*kp    )*D_ + d4);
      const float4 c = *(const float4*)(vbase + (size_t)(t0 + 2*kp + 1)*D_ + d4);
      const float av[4] = {a.x, a.y, a.z, a.w};
      const float cv[4] = {c.x, c.y, c.z, c.w};
      #pragma unroll
      for (int j = 0; j < 4; ++j) {
        const unsigned pk = (unsigned)(unsigned short)f2bf(av[j])
                          | ((unsigned)(unsigned short)f2bf(cv[j]) << 16);
        *(unsigned*)&sVT[d4 + j][2*kp] = pk;
      }
    }
    __syncthreads();

    int4 mk[4];
    #pragma unroll
    for (int mt = 0; mt < 4; ++mt)
      mk[mt] = *(const int4*)(mrow + t0 + mt*16 + quad*4);

    f32x4 st[4];
    #pragma unroll
    for (int mt = 0; mt < 4; ++mt) {
      f32x4 acc = (f32x4){0.f, 0.f, 0.f, 0.f};
      #pragma unroll
      for (int ks = 0; ks < 2; ++ks) {
        const bf16x8 kf = *(const bf16x8*)&sK[mt*16 + l15][ks*32 + quad*8];
        acc = __builtin_amdgcn_mfma_f32_16x16x32_bf16(kf, qf[ks], acc, 0, 0, 0);
      }
      st[mt] = acc;
    }

    float cmax = -3.0e38f;
    #pragma unroll
    for (int mt = 0; mt < 4; ++mt) {
      f32x4 s = st[mt];
      s.x = mk[mt].x ? s.x : MASKNEG;
      s.y = mk[mt].y ? s.y : MASKNEG;
      s.z = mk[mt].z ? s.z : MASKNEG;
      s.w = mk[mt].w ? s.w : MASKNEG;
      st[mt] = s;
      cmax = fmaxf(cmax, fmaxf(fmaxf(s.x, s.y), fmaxf(s.z, s.w)));
    }
    cmax = fmaxf(cmax, __shfl_xor(cmax, 16));
    cmax = fmaxf(cmax, __shfl_xor(cmax, 32));
    const float mnew  = fmaxf(m, cmax);
    const float alpha = fexp2(m - mnew);
    m = mnew;

    float lsum = 0.f;
    #pragma unroll
    for (int mt = 0; mt < 4; ++mt) {
      const float p0 = fexp2(st[mt].x - mnew);
      const float p1 = fexp2(st[mt].y - mnew);
      const float p2 = fexp2(st[mt].z - mnew);
      const float p3 = fexp2(st[mt].w - mnew);
      lsum += (p0 + p1) + (p2 + p3);
      bf16x4 pw; pw[0]=f2bf(p0); pw[1]=f2bf(p1); pw[2]=f2bf(p2); pw[3]=f2bf(p3);
      *(bf16x4*)&sP[wv][l15][mt*16 + quad*4] = pw;
    }
    lsum += __shfl_xor(lsum, 16);
    lsum += __shfl_xor(lsum, 32);
    l = l * alpha + lsum;

    const float ar0 = __shfl(alpha, quad*4 + 0);
    const float ar1 = __shfl(alpha, quad*4 + 1);
    const float ar2 = __shfl(alpha, quad*4 + 2);
    const float ar3 = __shfl(alpha, quad*4 + 3);
    #pragma unroll
    for (int dt = 0; dt < 4; ++dt) {
      O[dt].x *= ar0; O[dt].y *= ar1; O[dt].z *= ar2; O[dt].w *= ar3;
    }

    asm volatile("s_waitcnt lgkmcnt(0)" ::: "memory");

    const bf16x8 pf0 = *(const bf16x8*)&sP[wv][l15][quad*8];
    const bf16x8 pf1 = *(const bf16x8*)&sP[wv][l15][32 + quad*8];
    #pragma unroll
    for (int dt = 0; dt < 4; ++dt) {
      const bf16x8 vf0 = *(const bf16x8*)&sVT[dt*16 + l15][quad*8];
      const bf16x8 vf1 = *(const bf16x8*)&sVT[dt*16 + l15][32 + quad*8];
      O[dt] = __builtin_amdgcn_mfma_f32_16x16x32_bf16(pf0, vf0, O[dt], 0, 0, 0);
      O[dt] = __builtin_amdgcn_mfma_f32_16x16x32_bf16(pf1, vf1, O[dt], 0, 0, 0);
    }
  }

  float ir[4];
  #pragma unroll
  for (int r = 0; r < 4; ++r) ir[r] = 1.0f / __shfl(l, quad*4 + r);

  float* ob = outg + ((size_t)bh * S_ + q0 + wv*16) * D_;
  #pragma unroll
  for (int dt = 0; dt < 4; ++dt) {
    ob[(quad*4 + 0)*D_ + dt*16 + l15] = O[dt].x * ir[0];
    ob[(quad*4 + 1)*D_ + dt*16 + l15] = O[dt].y * ir[1];
    ob[(quad*4 + 2)*D_ + dt*16 + l15] = O[dt].z * ir[2];
    ob[(quad*4 + 3)*D_ + dt*16 + l15] = O[dt].w * ir[3];
  }
}

extern "C" void kernel_launch(void* const* d_in, const int* in_sizes, int n_in,
                              void* d_out, int out_size, void* d_ws, size_t ws_size,
                              hipStream_t stream) {
  const float* q    = (const float*)d_in[0];
  const float* k    = (const float*)d_in[1];
  const float* v    = (const float*)d_in[2];
  const int*   mask = (const int*)d_in[3];
  float* out = (float*)d_out;

  const size_t kvbytes = (size_t)B_ * H_ * S_ * D_ * 2;          // 8 MB each
  const size_t mbytes  = (size_t)B_ * S_ * NT * 8;               // 1 MB
  const size_t need    = 2 * kvbytes + mbytes;

  if (d_ws != nullptr && ws_size >= need) {
    short* kwp = (short*)d_ws;
    short* vwp = (short*)((char*)d_ws + kvbytes);
    unsigned long long* mwp = (unsigned long long*)((char*)d_ws + 2 * kvbytes);
    pack_all<<<dim3(2048), 256, 0, stream>>>(k, v, mask, kwp, vwp, mwp);
    attn_main<<<dim3(S_ / BQ, B_ * H_), 512, 0, stream>>>(q, kwp, vwp, mwp, out);
  } else {
    attn_fallback<<<dim3(S_ / 64, B_ * H_), 256, 0, stream>>>(q, k, v, mask, out);
  }
}